// Round 1
// baseline (7293.685 us; speedup 1.0000x reference)
//
#include <hip/hip_runtime.h>

#define TSEQ 512
#define BATCH 64
#define DIN 1024
#define HID 512
#define G4 2048
#define CHK 64

typedef __attribute__((ext_vector_type(8))) short short8;
typedef __attribute__((ext_vector_type(4))) float floatx4;

__device__ __forceinline__ floatx4 mfma16(short8 a, short8 b, floatx4 c) {
  return __builtin_amdgcn_mfma_f32_16x16x32_bf16(a, b, c, 0, 0, 0);
}

__device__ __forceinline__ unsigned short f2bf(float f) {
  unsigned int u = __float_as_uint(f);
  unsigned int r = (u + 0x7fffu + ((u >> 16) & 1u)) >> 16;
  return (unsigned short)r;
}

__device__ __forceinline__ float sigm(float x) { return 1.f / (1.f + __expf(-x)); }
__device__ __forceinline__ float tanh_f(float x) {
  float xx = fminf(fmaxf(x, -15.f), 15.f);
  float e = __expf(2.f * xx);
  return (e - 1.f) / (e + 1.f);
}

// Convert fp32 x -> bf16 (same [T][B][DIN] layout, k-contiguous for B-fragments)
__global__ void k_convert_x(const float* __restrict__ x, unsigned short* __restrict__ xbf, int n4) {
  int i = blockIdx.x * 256 + threadIdx.x;
  if (i >= n4) return;
  floatx4 v = reinterpret_cast<const floatx4*>(x)[i];
  union { unsigned short us[4]; unsigned long long ull; } pk;
  pk.us[0] = f2bf(v[0]); pk.us[1] = f2bf(v[1]); pk.us[2] = f2bf(v[2]); pk.us[3] = f2bf(v[3]);
  reinterpret_cast<unsigned long long*>(xbf)[i] = pk.ull;
}

// Pre-arrange W [L][2][2048][K] fp32 into bf16 MFMA A-fragment order, with rows
// permuted so row' = 4*unit + gate  (orig row = gate*512 + unit).
// One block = one (m-tile, k-step) of one (layer,dir); 64 threads = 64 lanes.
// Wf[(((mt*(K/32)+kt)*64)+lane)*8 + j] = W[perm(mt*16+(lane&15))][kt*32+(lane>>4)*8+j]
__global__ void k_prep_w(const float* __restrict__ W, unsigned short* __restrict__ Wf, int K) {
  int mt = blockIdx.x, kt = blockIdx.y, ld = blockIdx.z;
  int lane = threadIdx.x;
  int rp = mt * 16 + (lane & 15);
  int row = (rp & 3) * HID + (rp >> 2);
  int k0 = kt * 32 + (lane >> 4) * 8;
  const float* src = W + (size_t)ld * G4 * K + (size_t)row * K + k0;
  unsigned short* dst = Wf + (size_t)ld * G4 * K + (((size_t)mt * (K / 32) + kt) * 64 + lane) * 8;
  for (int j = 0; j < 8; ++j) dst[j] = f2bf(src[j]);
}

// biasf[l][d][row'] = b_ih[l][d][orig] + b_hh[l][d][orig], permuted like W rows.
__global__ void k_prep_bias(const float* __restrict__ bih, const float* __restrict__ bhh,
                            float* __restrict__ biasf) {
  int i = blockIdx.x * 256 + threadIdx.x;  // 0 .. 4*2048-1
  int ld = i >> 11;
  int rp = i & 2047;
  int row = (rp & 3) * HID + (rp >> 2);
  biasf[i] = bih[ld * G4 + row] + bhh[ld * G4 + row];
}

// Input projection for one T-chunk (both directions).
// D[g'][n=(t,b)] = sum_k Wih[g'][k] * xin[t][b][k], + bias, written to
// pre[dir][tloc][g'][b] (fp32). Grid: (G4/128, CHK/4, 2), 256 threads.
// Wave w handles t = tloc_base + w, all 64 b (4 n-tiles), 8 m-tiles (128 g' rows).
__global__ __launch_bounds__(256, 2) void k_proj(
    const unsigned short* __restrict__ xin,   // [T][B][DIN] bf16
    const unsigned short* __restrict__ Wf,    // this layer: [2][G4*DIN] frag order
    const float* __restrict__ biasf,          // this layer: [2][G4] permuted
    float* __restrict__ pre,                  // [2][CHK][G4][B]
    int t0) {
  const int dir = blockIdx.z;
  const int w = threadIdx.x >> 6;
  const int lane = threadIdx.x & 63;
  const int quad = lane >> 4, col = lane & 15;
  const int tloc = blockIdx.y * 4 + w;
  const int tg = dir ? (TSEQ - 1 - (t0 + tloc)) : (t0 + tloc);
  const unsigned short* Wd = Wf + (size_t)dir * G4 * DIN;
  const unsigned short* xrow = xin + (size_t)tg * BATCH * DIN;

  floatx4 acc[8][4];
#pragma unroll
  for (int mi = 0; mi < 8; ++mi)
#pragma unroll
    for (int ni = 0; ni < 4; ++ni) acc[mi][ni] = (floatx4){0.f, 0.f, 0.f, 0.f};

#pragma unroll 4
  for (int kt = 0; kt < 32; ++kt) {
    short8 bfr[4];
#pragma unroll
    for (int ni = 0; ni < 4; ++ni) {
      int b = ni * 16 + col;
      bfr[ni] = *reinterpret_cast<const short8*>(xrow + (size_t)b * DIN + kt * 32 + quad * 8);
    }
#pragma unroll
    for (int mi = 0; mi < 8; ++mi) {
      size_t mt = (size_t)(blockIdx.x * 8 + mi);
      short8 afr = *reinterpret_cast<const short8*>(Wd + ((mt * 32 + kt) * 64 + lane) * 8);
#pragma unroll
      for (int ni = 0; ni < 4; ++ni) acc[mi][ni] = mfma16(afr, bfr[ni], acc[mi][ni]);
    }
  }

#pragma unroll
  for (int mi = 0; mi < 8; ++mi) {
    int gbase = blockIdx.x * 128 + mi * 16 + quad * 4;
#pragma unroll
    for (int r = 0; r < 4; ++r) {
      float bv = biasf[dir * G4 + gbase + r];
      float* prow = pre + (((size_t)dir * CHK + tloc) * G4 + gbase + r) * BATCH;
#pragma unroll
      for (int ni = 0; ni < 4; ++ni) prow[ni * 16 + col] = acc[mi][ni][r] + bv;
    }
  }
}

// One recurrence step, both directions (grid.y), g' in blocks of 32 (grid.x=64).
// acc (from pre) += Whh[g'][k] * h_prev[b][k]; then LSTM nonlinearity.
// Because rows are permuted (row' = 4u+gate), lane regs 0..3 are exactly
// (i,f,g,o) of unit u = gb*8 + mi*4 + quad for batch b = w*16 + col.
__global__ __launch_bounds__(256, 4) void k_step(
    const unsigned short* __restrict__ Whhf,  // this layer: [2][G4*HID] frag order
    const float* __restrict__ pre,            // [2][CHK][G4][B]
    unsigned short* act1bf,                   // [T][B][DIN] bf16 (layer-1 h, layer-2 input)
    unsigned short* hT2,                      // [2 slots][2 dir][B][HID] bf16
    float* cst,                               // [2 layer][2 dir][HID][B] fp32
    float* __restrict__ dout,                 // [T][B][DIN] fp32
    int s, int jloc, int layer) {
  const int dir = blockIdx.y;
  const int gb = blockIdx.x;
  const int w = threadIdx.x >> 6;
  const int lane = threadIdx.x & 63;
  const int quad = lane >> 4, col = lane & 15;
  const int b = w * 16 + col;
  const int t = dir ? (TSEQ - 1 - s) : s;

  floatx4 acc[2];
#pragma unroll
  for (int mi = 0; mi < 2; ++mi) {
#pragma unroll
    for (int r = 0; r < 4; ++r) {
      int gp = gb * 32 + mi * 16 + quad * 4 + r;
      acc[mi][r] = pre[(((size_t)dir * CHK + jloc) * G4 + gp) * BATCH + b];
    }
  }

  if (s > 0) {
    const unsigned short* hprev;
    int hstride;
    if (layer == 0) {
      int tp = dir ? t + 1 : t - 1;
      hprev = act1bf + (size_t)tp * BATCH * DIN + dir * HID;
      hstride = DIN;
    } else {
      hprev = hT2 + (size_t)(((s - 1) & 1) * 2 + dir) * BATCH * HID;
      hstride = HID;
    }
    const unsigned short* Wd = Whhf + (size_t)dir * G4 * HID;
#pragma unroll
    for (int kt = 0; kt < 16; ++kt) {
      short8 bfr = *reinterpret_cast<const short8*>(hprev + (size_t)b * hstride + kt * 32 + quad * 8);
#pragma unroll
      for (int mi = 0; mi < 2; ++mi) {
        size_t mt = (size_t)(gb * 2 + mi);
        short8 afr = *reinterpret_cast<const short8*>(Wd + ((mt * 16 + kt) * 64 + lane) * 8);
        acc[mi] = mfma16(afr, bfr, acc[mi]);
      }
    }
  }

  float* cl = cst + ((size_t)layer * 2 + dir) * HID * BATCH;
#pragma unroll
  for (int mi = 0; mi < 2; ++mi) {
    int u = gb * 8 + mi * 4 + quad;
    float si = sigm(acc[mi][0]);
    float sf = sigm(acc[mi][1]);
    float tg = tanh_f(acc[mi][2]);
    float so = sigm(acc[mi][3]);
    float cprev = (s > 0) ? cl[u * BATCH + b] : 0.f;
    float c = cprev * si + sf * tg;
    float h = tanh_f(c) * so;
    cl[u * BATCH + b] = c;
    if (layer == 0) {
      act1bf[((size_t)t * BATCH + b) * DIN + dir * HID + u] = f2bf(h);
    } else {
      hT2[((size_t)((s & 1) * 2 + dir) * BATCH + b) * HID + u] = f2bf(h);
      dout[((size_t)t * BATCH + b) * DIN + dir * HID + u] = h;
    }
  }
}

extern "C" void kernel_launch(void* const* d_in, const int* in_sizes, int n_in,
                              void* d_out, int out_size, void* d_ws, size_t ws_size,
                              hipStream_t stream) {
  const float* x = (const float*)d_in[0];
  const float* W_ih = (const float*)d_in[1];
  const float* b_ih = (const float*)d_in[2];
  const float* W_hh = (const float*)d_in[3];
  const float* b_hh = (const float*)d_in[4];
  float* dout = (float*)d_out;

  char* p = (char*)d_ws;
  auto alloc = [&](size_t bytes) {
    char* r = p;
    p += (bytes + 255) & ~(size_t)255;
    return r;
  };
  unsigned short* xbf    = (unsigned short*)alloc((size_t)TSEQ * BATCH * DIN * 2);
  unsigned short* act1bf = (unsigned short*)alloc((size_t)TSEQ * BATCH * DIN * 2);
  float*          pre    = (float*)alloc((size_t)2 * CHK * G4 * BATCH * 4);
  unsigned short* Wihf   = (unsigned short*)alloc((size_t)4 * G4 * DIN * 2);
  unsigned short* Whhf   = (unsigned short*)alloc((size_t)4 * G4 * HID * 2);
  float*          biasf  = (float*)alloc((size_t)4 * G4 * 4);
  float*          cst    = (float*)alloc((size_t)4 * HID * BATCH * 4);
  unsigned short* hT2    = (unsigned short*)alloc((size_t)4 * BATCH * HID * 2);

  size_t required = (size_t)(p - (char*)d_ws);
  if (ws_size < required) return;  // fail visibly rather than corrupt memory

  int n4 = TSEQ * BATCH * DIN / 4;
  k_convert_x<<<dim3((n4 + 255) / 256), dim3(256), 0, stream>>>(x, xbf, n4);
  k_prep_w<<<dim3(G4 / 16, DIN / 32, 4), dim3(64), 0, stream>>>(W_ih, Wihf, DIN);
  k_prep_w<<<dim3(G4 / 16, HID / 32, 4), dim3(64), 0, stream>>>(W_hh, Whhf, HID);
  k_prep_bias<<<dim3(32), dim3(256), 0, stream>>>(b_ih, b_hh, biasf);

  for (int l = 0; l < 2; ++l) {
    const unsigned short* xin = l ? act1bf : xbf;
    const unsigned short* Wfl = Wihf + (size_t)l * 2 * G4 * DIN;
    const unsigned short* Whl = Whhf + (size_t)l * 2 * G4 * HID;
    const float* bfl = biasf + (size_t)l * 2 * G4;
    for (int c = 0; c < TSEQ / CHK; ++c) {
      k_proj<<<dim3(G4 / 128, CHK / 4, 2), dim3(256), 0, stream>>>(xin, Wfl, bfl, pre, c * CHK);
      for (int j = 0; j < CHK; ++j) {
        k_step<<<dim3(G4 / 32, 2), dim3(256), 0, stream>>>(Whl, pre, act1bf, hT2, cst, dout,
                                                           c * CHK + j, j, l);
      }
    }
  }
  (void)in_sizes; (void)n_in; (void)out_size;
}